// Round 1
// baseline (9030.136 us; speedup 1.0000x reference)
//
#include <hip/hip_runtime.h>
#include <cstdint>
#include <cstddef>

typedef __attribute__((ext_vector_type(8))) short bf16x8;
typedef __attribute__((ext_vector_type(4))) float f32x4;

#define DEVI __device__ __forceinline__

constexpr int B = 256, S = 128, V = 128, C = 16, H = 1024, Z = 256, NSTEP = 128;
constexpr int VC = V * C;   // 2048
constexpr int G3 = 3 * H;   // 3072

DEVI unsigned short f2bf(float f) {
  unsigned u = __float_as_uint(f);
  u += 0x7fffu + ((u >> 16) & 1u);   // RNE
  return (unsigned short)(u >> 16);
}
DEVI float sigm(float x) { return 1.0f / (1.0f + expf(-x)); }

// ---------------- prep kernels ----------------
__global__ void k_cvt(const float* __restrict__ src, unsigned short* __restrict__ dst, int n) {
  for (int i = blockIdx.x * 256 + threadIdx.x; i < n; i += gridDim.x * 256)
    dst[i] = f2bf(src[i]);
}

// x (B,V,S) -> xtb (S, B*V) bf16   (time-major encoder input)
__global__ void k_xt(const float* __restrict__ x, unsigned short* __restrict__ xtb) {
  __shared__ float tile[32][33];
  int sb = blockIdx.x * 32, rb = blockIdx.y * 32;
  int tx = threadIdx.x, ty = threadIdx.y;
  for (int i = ty; i < 32; i += 8) tile[i][tx] = x[(size_t)(rb + i) * S + sb + tx];
  __syncthreads();
  for (int i = ty; i < 32; i += 8)
    xtb[(size_t)(sb + i) * (B * V) + rb + tx] = f2bf(tile[tx][i]);
}

// c1_Wih (G3, VC+Z) cols [0,VC) -> WT (VC, G3) fp32 (row gather for one-hot feedback)
__global__ void k_wt(const float* __restrict__ w, float* __restrict__ wt) {
  __shared__ float tile[32][33];
  int vb = blockIdx.x * 32, nb = blockIdx.y * 32;
  int tx = threadIdx.x, ty = threadIdx.y;
  for (int i = ty; i < 32; i += 8) tile[i][tx] = w[(size_t)(nb + i) * (VC + Z) + vb + tx];
  __syncthreads();
  for (int i = ty; i < 32; i += 8)
    wt[(size_t)(vb + i) * G3 + nb + tx] = tile[tx][i];
}

// ---------------- MFMA GEMM: C[m][n] = sum_k A[m][k]*Bw[n][k] ----------------
struct GemmJob {
  const unsigned short* A;   // M x K bf16 row-major
  const unsigned short* Bw;  // N x K bf16 row-major (B^T form)
  float* Cm;                 // M x N fp32
  int lda, ldb, ldc, K;
};
struct GemmJobs4 { GemmJob j[4]; };

typedef __attribute__((address_space(1))) const unsigned short* gas_p;
typedef __attribute__((address_space(3))) unsigned short* las_p;

__global__ __launch_bounds__(256) void k_gemm(GemmJobs4 jobs) {
  GemmJob jb = jobs.j[blockIdx.z];
  const int tid = threadIdx.x;
  const int wave = tid >> 6;
  const int lane = tid & 63;
  const int bn = blockIdx.x * 64;
  const int bm = blockIdx.y * 64;
  __shared__ unsigned short As[64 * 64];
  __shared__ unsigned short Bs[64 * 64];
  f32x4 acc[2][2] = {};
  const int wm = ((wave >> 1) & 1) * 32;
  const int wn = (wave & 1) * 32;
  const int rrow = (lane >> 3) & 7;   // staging: row-within-8
  const int pc = lane & 7;            // staging: physical 16B chunk
  const int l15 = lane & 15;
  const int l4 = lane >> 4;

  const int nkt = jb.K >> 6;
  for (int kt = 0; kt < nkt; ++kt) {
    const int kbase = kt << 6;
    __syncthreads();  // previous tile's reads done before overwrite
    // stage 64x64 bf16 A and B tiles: linear LDS dest, inverse-swizzled global src.
    // physical slot (row, pc) holds logical chunk (pc ^ (row&7))  [XOR involution]
#pragma unroll
    for (int i = 0; i < 2; ++i) {
      int row = wave * 16 + i * 8 + rrow;
      int c = pc ^ (row & 7);
      const unsigned short* ga = jb.A + (size_t)(bm + row) * jb.lda + kbase + c * 8;
      __builtin_amdgcn_global_load_lds((gas_p)ga, (las_p)&As[(wave * 16 + i * 8) * 64], 16, 0, 0);
      const unsigned short* gb = jb.Bw + (size_t)(bn + row) * jb.ldb + kbase + c * 8;
      __builtin_amdgcn_global_load_lds((gas_p)gb, (las_p)&Bs[(wave * 16 + i * 8) * 64], 16, 0, 0);
    }
    __syncthreads();
#pragma unroll
    for (int kf = 0; kf < 2; ++kf) {
      int ch = (kf << 2) + l4;   // logical 16B chunk for this lane's k-slice
      bf16x8 af[2], bfr[2];
#pragma unroll
      for (int mi = 0; mi < 2; ++mi) {
        int row = wm + mi * 16 + l15;
        af[mi] = *(const bf16x8*)&As[row * 64 + ((ch ^ (row & 7)) << 3)];
      }
#pragma unroll
      for (int ni = 0; ni < 2; ++ni) {
        int row = wn + ni * 16 + l15;
        bfr[ni] = *(const bf16x8*)&Bs[row * 64 + ((ch ^ (row & 7)) << 3)];
      }
#pragma unroll
      for (int mi = 0; mi < 2; ++mi)
#pragma unroll
        for (int ni = 0; ni < 2; ++ni)
          acc[mi][ni] = __builtin_amdgcn_mfma_f32_16x16x32_bf16(af[mi], bfr[ni], acc[mi][ni], 0, 0, 0);
    }
  }
  // epilogue: C/D layout col=lane&15, row=(lane>>4)*4+reg  [m89-verified]
#pragma unroll
  for (int mi = 0; mi < 2; ++mi)
#pragma unroll
    for (int ni = 0; ni < 2; ++ni) {
      int m0 = bm + wm + mi * 16 + l4 * 4;
      int n0 = bn + wn + ni * 16 + l15;
#pragma unroll
      for (int r = 0; r < 4; ++r)
        jb.Cm[(size_t)(m0 + r) * jb.ldc + n0] = acc[mi][ni][r];
    }
}

// ---------------- GRU combines ----------------
__global__ void k_enc_combine(const float* __restrict__ gif, const float* __restrict__ ghf,
                              const float* __restrict__ gib, const float* __restrict__ ghb,
                              const float* __restrict__ bihf, const float* __restrict__ bhhf,
                              const float* __restrict__ bihb, const float* __restrict__ bhhb,
                              float* __restrict__ hf, unsigned short* __restrict__ hfb,
                              float* __restrict__ hb, unsigned short* __restrict__ hbb) {
  int idx = blockIdx.x * 256 + threadIdx.x;
  int b = idx >> 10, jj = idx & (H - 1);
  const float *gi, *gh, *bih, *bhh; float* h; unsigned short* hB;
  if (blockIdx.y == 0) { gi = gif; gh = ghf; bih = bihf; bhh = bhhf; h = hf; hB = hfb; }
  else                 { gi = gib; gh = ghb; bih = bihb; bhh = bhhb; h = hb; hB = hbb; }
  int base = b * G3 + jj;
  float ir = gi[base] + bih[jj];
  float iz = gi[base + H] + bih[H + jj];
  float in_ = gi[base + 2 * H] + bih[2 * H + jj];
  float hr = gh[base] + bhh[jj];
  float hz = gh[base + H] + bhh[H + jj];
  float hn = gh[base + 2 * H] + bhh[2 * H + jj];
  float r = sigm(ir + hr);
  float zg = sigm(iz + hz);
  float n = tanhf(in_ + r * hn);
  float hnew = (1.f - zg) * n + zg * h[idx];
  h[idx] = hnew;
  hB[idx] = f2bf(hnew);
}

__global__ void k_combine1(const float* __restrict__ zpart, const float* __restrict__ WT,
                           const float* __restrict__ gh1, const float* __restrict__ bhh,
                           const int* __restrict__ idxb,
                           float* __restrict__ h1, unsigned short* __restrict__ h1b) {
  int idx = blockIdx.x * 256 + threadIdx.x;
  int b = idx >> 10, jj = idx & (H - 1);
  const float* wrow = WT + (size_t)idxb[b] * G3;   // one-hot column gather (pre-transposed)
  int base = b * G3 + jj;
  float ir = zpart[base] + wrow[jj];               // zpart already includes c1_bih
  float iz = zpart[base + H] + wrow[H + jj];
  float in_ = zpart[base + 2 * H] + wrow[2 * H + jj];
  float hr = gh1[base] + bhh[jj];
  float hz = gh1[base + H] + bhh[H + jj];
  float hn = gh1[base + 2 * H] + bhh[2 * H + jj];
  float r = sigm(ir + hr);
  float zg = sigm(iz + hz);
  float n = tanhf(in_ + r * hn);
  float hnew = (1.f - zg) * n + zg * h1[idx];
  h1[idx] = hnew;
  h1b[idx] = f2bf(hnew);
}

__global__ void k_combine2(const float* __restrict__ gi2, const float* __restrict__ gh2,
                           const float* __restrict__ bih, const float* __restrict__ bhh,
                           const float* __restrict__ h2prev,
                           float* __restrict__ h2, unsigned short* __restrict__ h2b) {
  int idx = blockIdx.x * 256 + threadIdx.x;
  int b = idx >> 10, jj = idx & (H - 1);
  int base = b * G3 + jj;
  float ir = gi2[base] + bih[jj];
  float iz = gi2[base + H] + bih[H + jj];
  float in_ = gi2[base + 2 * H] + bih[2 * H + jj];
  float hr = gh2[base] + bhh[jj];
  float hz = gh2[base + H] + bhh[H + jj];
  float hn = gh2[base + 2 * H] + bhh[2 * H + jj];
  float r = sigm(ir + hr);
  float zg = sigm(iz + hz);
  float n = tanhf(in_ + r * hn);
  float hnew = (1.f - zg) * n + zg * h2prev[idx];
  h2[idx] = hnew;
  h2b[idx] = f2bf(hnew);
}

// ---------------- latent head ----------------
__global__ __launch_bounds__(256) void k_mu_var_z(const float* __restrict__ hf, const float* __restrict__ hb,
                                                  const float* __restrict__ Wmu, const float* __restrict__ bmu,
                                                  const float* __restrict__ Wvar, const float* __restrict__ bvar,
                                                  const float* __restrict__ noise,
                                                  float* __restrict__ omu, float* __restrict__ ovar,
                                                  float* __restrict__ oz, float* __restrict__ zws) {
  __shared__ float e[2 * H];
  int b = blockIdx.x, t = threadIdx.x;
  for (int i = 0; i < 2 * H / 256; ++i) {
    int k = t + i * 256;
    e[k] = (k < H) ? hf[b * H + k] : hb[b * H + k - H];
  }
  __syncthreads();
  const float* wm = Wmu + (size_t)t * 2 * H;
  const float* wv = Wvar + (size_t)t * 2 * H;
  float am = bmu[t], av = bvar[t];
  for (int k = 0; k < 2 * H; ++k) { am += e[k] * wm[k]; av += e[k] * wv[k]; }
  float vv = expf(av);
  float zz = am + vv * noise[b * Z + t];
  omu[b * Z + t] = am; ovar[b * Z + t] = vv; oz[b * Z + t] = zz; zws[b * Z + t] = zz;
}

// zpart[b][n] = c1_bih[n] + sum_k z[b][k] * c1_Wih[n][VC+k]   (step-invariant)
__global__ void k_zpart(const float* __restrict__ z, const float* __restrict__ c1Wih,
                        const float* __restrict__ bih, float* __restrict__ zpart) {
  int idx = blockIdx.x * 256 + threadIdx.x;
  int b = idx / G3, n = idx % G3;
  const float* w = c1Wih + (size_t)n * (VC + Z) + VC;
  const float* zr = z + b * Z;
  float a = bih[n];
  for (int k = 0; k < Z; ++k) a += zr[k] * w[k];
  zpart[idx] = a;
}

__global__ void k_h1init(const float* __restrict__ z, const float* __restrict__ Winit,
                         const float* __restrict__ binit,
                         float* __restrict__ h1, unsigned short* __restrict__ h1b,
                         int* __restrict__ idxb) {
  int idx = blockIdx.x * 256 + threadIdx.x;
  int b = idx >> 10, jj = idx & (H - 1);
  const float* w = Winit + (size_t)jj * Z;
  const float* zr = z + b * Z;
  float a = binit[jj];
  for (int k = 0; k < Z; ++k) a += zr[k] * w[k];
  float t = tanhf(a);
  h1[idx] = t; h1b[idx] = f2bf(t);
  if (idx < B) idxb[idx] = VC - 1;   // out0 one-hot at last index
}

// ---------------- softmax + argmax + staging ----------------
__global__ __launch_bounds__(256) void k_softmax(const float* __restrict__ logits,
                                                 const float* __restrict__ bout,
                                                 float* __restrict__ lsbuf, int slot,
                                                 int* __restrict__ idxb) {
  int b = blockIdx.x, t = threadIdx.x;
  __shared__ float ls[VC];
  __shared__ float rv[256];
  __shared__ int ri[256];
  for (int i = 0; i < VC / 256; ++i) {
    int n = t + i * 256;
    ls[n] = logits[(size_t)b * VC + n] + bout[n];
  }
  __syncthreads();
  if (t < V) {   // log-softmax over C (stride-V groups)
    float m = -1e30f;
    for (int c = 0; c < C; ++c) m = fmaxf(m, ls[c * V + t]);
    float s = 0.f;
    for (int c = 0; c < C; ++c) s += expf(ls[c * V + t] - m);
    float lse = m + logf(s);
    for (int c = 0; c < C; ++c) ls[c * V + t] -= lse;
  }
  __syncthreads();
  // argmax over VC, first-index tie-break (match jnp.argmax)
  float bv = -1e30f; int bi = 0;
  for (int i = 0; i < VC / 256; ++i) {
    int n = i * 256 + t;
    float v = ls[n];
    if (v > bv) { bv = v; bi = n; }
  }
  rv[t] = bv; ri[t] = bi;
  __syncthreads();
  for (int s2 = 128; s2 > 0; s2 >>= 1) {
    if (t < s2) {
      float v2 = rv[t + s2]; int i2 = ri[t + s2];
      if (v2 > rv[t] || (v2 == rv[t] && i2 < ri[t])) { rv[t] = v2; ri[t] = i2; }
    }
    __syncthreads();
  }
  if (t == 0) idxb[b] = ri[0];
  float* dst = lsbuf + (size_t)slot * B * VC + (size_t)b * VC;
  for (int i = 0; i < VC / 256; ++i) { int n = t + i * 256; dst[n] = ls[n]; }
}

// flush 16 staged steps -> recon (b, VC, NSTEP): 64B contiguous per thread
__global__ void k_flush(const float* __restrict__ lsbuf, float* __restrict__ recon, int t0) {
  int idx = blockIdx.x * 256 + threadIdx.x;   // over B*VC
  float* dst = recon + (size_t)idx * NSTEP + t0;
#pragma unroll
  for (int j = 0; j < 16; ++j) dst[j] = lsbuf[(size_t)j * B * VC + idx];
}

// ---------------- host orchestration ----------------
extern "C" void kernel_launch(void* const* d_in, const int* in_sizes, int n_in,
                              void* d_out, int out_size, void* d_ws, size_t ws_size,
                              hipStream_t stream) {
  const float* x        = (const float*)d_in[0];
  const float* noise    = (const float*)d_in[1];
  const float* gruf_Wih = (const float*)d_in[2];
  const float* gruf_Whh = (const float*)d_in[3];
  const float* gruf_bih = (const float*)d_in[4];
  const float* gruf_bhh = (const float*)d_in[5];
  const float* grub_Wih = (const float*)d_in[6];
  const float* grub_Whh = (const float*)d_in[7];
  const float* grub_bih = (const float*)d_in[8];
  const float* grub_bhh = (const float*)d_in[9];
  const float* Wmu      = (const float*)d_in[10];
  const float* bmu      = (const float*)d_in[11];
  const float* Wvar     = (const float*)d_in[12];
  const float* bvar     = (const float*)d_in[13];
  const float* Winit    = (const float*)d_in[14];
  const float* binit    = (const float*)d_in[15];
  const float* c1_Wih   = (const float*)d_in[16];
  const float* c1_Whh   = (const float*)d_in[17];
  const float* c1_bih   = (const float*)d_in[18];
  const float* c1_bhh   = (const float*)d_in[19];
  const float* c2_Wih   = (const float*)d_in[20];
  const float* c2_Whh   = (const float*)d_in[21];
  const float* c2_bih   = (const float*)d_in[22];
  const float* c2_bhh   = (const float*)d_in[23];
  const float* Wout     = (const float*)d_in[24];
  const float* bout     = (const float*)d_in[25];

  float* omu = (float*)d_out;
  float* ovar = omu + B * Z;
  float* oz = ovar + B * Z;
  float* orecon = oz + B * Z;

  char* p = (char*)d_ws;
  auto carve = [&](size_t bytes) { char* r = p; p += (bytes + 255) & ~(size_t)255; return r; };
  unsigned short* wihf_b  = (unsigned short*)carve((size_t)G3 * V * 2);
  unsigned short* whhf_b  = (unsigned short*)carve((size_t)G3 * H * 2);
  unsigned short* wihb_b  = (unsigned short*)carve((size_t)G3 * V * 2);
  unsigned short* whhb_b  = (unsigned short*)carve((size_t)G3 * H * 2);
  unsigned short* wc1hh_b = (unsigned short*)carve((size_t)G3 * H * 2);
  unsigned short* wc2ih_b = (unsigned short*)carve((size_t)G3 * H * 2);
  unsigned short* wc2hh_b = (unsigned short*)carve((size_t)G3 * H * 2);
  unsigned short* wout_b  = (unsigned short*)carve((size_t)VC * H * 2);
  unsigned short* xtb     = (unsigned short*)carve((size_t)S * B * V * 2);
  unsigned short* hfb     = (unsigned short*)carve((size_t)B * H * 2);
  unsigned short* hbb     = (unsigned short*)carve((size_t)B * H * 2);
  unsigned short* h1b     = (unsigned short*)carve((size_t)B * H * 2);
  unsigned short* h2b     = (unsigned short*)carve((size_t)B * H * 2);
  float* WT     = (float*)carve((size_t)VC * G3 * 4);
  float* zpart  = (float*)carve((size_t)B * G3 * 4);
  float* g0     = (float*)carve((size_t)B * G3 * 4);
  float* g1     = (float*)carve((size_t)B * G3 * 4);
  float* g2     = (float*)carve((size_t)B * G3 * 4);
  float* g3     = (float*)carve((size_t)B * G3 * 4);
  float* hf     = (float*)carve((size_t)B * H * 4);
  float* hb     = (float*)carve((size_t)B * H * 4);
  float* h1     = (float*)carve((size_t)B * H * 4);
  float* h2     = (float*)carve((size_t)B * H * 4);
  float* zws    = (float*)carve((size_t)B * Z * 4);
  float* logits = (float*)carve((size_t)B * VC * 4);
  float* lsbuf  = (float*)carve((size_t)16 * B * VC * 4);
  int* idxb     = (int*)carve((size_t)B * 4);

  dim3 blk(256);

  // weight conversions (one-time per call; cheap)
  auto cvt = [&](const float* s, unsigned short* d, int n) {
    int nb = (n + 255) / 256; if (nb > 2048) nb = 2048;
    k_cvt<<<nb, blk, 0, stream>>>(s, d, n);
  };
  cvt(gruf_Wih, wihf_b, G3 * V);
  cvt(gruf_Whh, whhf_b, G3 * H);
  cvt(grub_Wih, wihb_b, G3 * V);
  cvt(grub_Whh, whhb_b, G3 * H);
  cvt(c1_Whh, wc1hh_b, G3 * H);
  cvt(c2_Wih, wc2ih_b, G3 * H);
  cvt(c2_Whh, wc2hh_b, G3 * H);
  cvt(Wout, wout_b, VC * H);
  k_xt<<<dim3(S / 32, (B * V) / 32), dim3(32, 8), 0, stream>>>(x, xtb);
  k_wt<<<dim3(VC / 32, G3 / 32), dim3(32, 8), 0, stream>>>(c1_Wih, WT);

  hipMemsetAsync(hf, 0, (size_t)B * H * 4, stream);
  hipMemsetAsync(hb, 0, (size_t)B * H * 4, stream);
  hipMemsetAsync(hfb, 0, (size_t)B * H * 2, stream);
  hipMemsetAsync(hbb, 0, (size_t)B * H * 2, stream);

  // ---------------- encoder ----------------
  for (int s = 0; s < S; ++s) {
    GemmJobs4 jj;
    jj.j[0] = { xtb + (size_t)s * B * V,           wihf_b, g0, V, V, G3, V };
    jj.j[1] = { hfb,                               whhf_b, g1, H, H, G3, H };
    jj.j[2] = { xtb + (size_t)(S - 1 - s) * B * V, wihb_b, g2, V, V, G3, V };
    jj.j[3] = { hbb,                               whhb_b, g3, H, H, G3, H };
    k_gemm<<<dim3(G3 / 64, B / 64, 4), blk, 0, stream>>>(jj);
    k_enc_combine<<<dim3(B * H / 256, 2), blk, 0, stream>>>(
        g0, g1, g2, g3, gruf_bih, gruf_bhh, grub_bih, grub_bhh, hf, hfb, hb, hbb);
  }

  k_mu_var_z<<<B, blk, 0, stream>>>(hf, hb, Wmu, bmu, Wvar, bvar, noise, omu, ovar, oz, zws);
  k_zpart<<<B * G3 / 256, blk, 0, stream>>>(zws, c1_Wih, c1_bih, zpart);
  k_h1init<<<B * H / 256, blk, 0, stream>>>(zws, Winit, binit, h1, h1b, idxb);

  // ---------------- decoder ----------------
  for (int t = 0; t < NSTEP; ++t) {
    GemmJobs4 ja;
    ja.j[0] = { h1b, wc1hh_b, g0, H, H, G3, H };
    ja.j[1] = ja.j[0]; ja.j[2] = ja.j[0]; ja.j[3] = ja.j[0];
    k_gemm<<<dim3(G3 / 64, B / 64, 1), blk, 0, stream>>>(ja);
    k_combine1<<<B * H / 256, blk, 0, stream>>>(zpart, WT, g0, c1_bhh, idxb, h1, h1b);

    GemmJobs4 jc;
    jc.j[0] = { h1b,                     wc2ih_b, g1, H, H, G3, H };
    jc.j[1] = { (t == 0 ? h1b : h2b),    wc2hh_b, g2, H, H, G3, H };
    jc.j[2] = jc.j[0]; jc.j[3] = jc.j[0];
    k_gemm<<<dim3(G3 / 64, B / 64, 2), blk, 0, stream>>>(jc);
    k_combine2<<<B * H / 256, blk, 0, stream>>>(g1, g2, c2_bih, c2_bhh,
                                                (t == 0 ? h1 : h2), h2, h2b);

    GemmJobs4 jl;
    jl.j[0] = { h2b, wout_b, logits, H, H, VC, H };
    jl.j[1] = jl.j[0]; jl.j[2] = jl.j[0]; jl.j[3] = jl.j[0];
    k_gemm<<<dim3(VC / 64, B / 64, 1), blk, 0, stream>>>(jl);

    k_softmax<<<B, blk, 0, stream>>>(logits, bout, lsbuf, t & 15, idxb);
    if ((t & 15) == 15)
      k_flush<<<B * VC / 256, blk, 0, stream>>>(lsbuf, orecon, t - 15);
  }
}